// Round 6
// baseline (27.542 us; speedup 1.0000x reference)
//
#include <hip/hip_runtime.h>
#include <math.h>

// EdgeConstructor: out[b][i][j] = { dR(i,j), mass(i,j) } for B=256, N=256.
// v6: moving-write-window structure. 512 blocks (2/CU), each handles 4 strips
// (s = bid + 512*t) so the chip's concurrent stores stay within a ~33 MB
// contiguous window (mimics fillBuffer's 6.9 TB/s sequential-front pattern,
// vs v5's 2048 concurrent strips at 4.97 TB/s). Double-buffered LDS node
// features + prefetched next-strip x load; only strip 0's phase-1 exposed.

#define BATCH 256
#define NN 256
#define TI 32          // rows per strip
#define GRID 512
#define SPT 4          // strips per block (GRID*SPT = 256*256/TI = 2048)

typedef float f4 __attribute__((ext_vector_type(4)));

__device__ __forceinline__ void node_features(const float4 v,
    float& eta, float& phi, float& E, float& px, float& py, float& pz, float& m2n) {
    const float pt = v.x;
    eta = v.y; phi = v.z; E = v.w;
    // phi, eta in [0,1): fast HW transcendentals, no range reduction needed.
    const float sp = __sinf(phi);
    const float cp = __cosf(phi);
    const float ex = __expf(eta);
    px = pt * cp;
    py = pt * sp;
    pz = pt * 0.5f * (ex - __builtin_amdgcn_rcpf(ex));  // sinh(eta)
    const float p2 = fmaf(px, px, fmaf(py, py, pz * pz));
    m2n = fmaf(E, E, -p2);
}

__global__ __launch_bounds__(256)
void edge_kernel(const float* __restrict__ x, float* __restrict__ out) {
    const int tid = threadIdx.x;
    const int bid = blockIdx.x;

    __shared__ f4 s_a[2][NN];  // {eta, phi, E, m2}
    __shared__ f4 s_b[2][NN];  // {px, py, pz, 0}

    const float TWO_PI     = 6.28318530717958647692f;
    const float INV_TWO_PI = 0.15915494309189533577f;

    // Phase 1 for strip 0
    float eta, phi, E, px, py, pz, m2n;
    {
        const int b0 = bid >> 3;
        const float4 v = reinterpret_cast<const float4*>(x)[b0 * NN + tid];
        node_features(v, eta, phi, E, px, py, pz, m2n);
        f4 a; a.x = eta; a.y = phi; a.z = E;  a.w = m2n;
        f4 bb; bb.x = px; bb.y = py; bb.z = pz; bb.w = 0.0f;
        s_a[0][tid] = a;
        s_b[0][tid] = bb;
    }
    __syncthreads();

#pragma unroll
    for (int t = 0; t < SPT; ++t) {
        const int s   = bid + t * GRID;
        const int b   = s >> 3;
        const int i0  = (s & 7) * TI;
        const int buf = t & 1;

        // Prefetch next strip's node data (different batch) — issued before
        // the store loop, consumed after it; latency hides under the stores.
        float4 nv;
        if (t < SPT - 1) {
            const int nb = (bid + (t + 1) * GRID) >> 3;
            nv = reinterpret_cast<const float4*>(x)[nb * NN + tid];
        }

        float2* outp = reinterpret_cast<float2*>(out)
                     + ((size_t)b * NN + (size_t)i0) * NN + tid;

#pragma unroll 8
        for (int r = 0; r < TI; ++r) {
            const int i = i0 + r;
            // row-i values: wave-uniform LDS broadcast, 2x ds_read_b128
            const f4 a  = s_a[buf][i];
            const f4 bb = s_b[buf][i];

            const float deta = a.x - eta;
            float d = a.y - phi;
            // jnp.mod(d + pi, 2pi) - pi  ==  d - 2pi*floor(d/2pi + 0.5)
            const float f = floorf(fmaf(d, INV_TWO_PI, 0.5f));
            d = fmaf(-TWO_PI, f, d);
            const float r2 = fmaxf(fmaf(deta, deta, d * d), 1e-12f);
            const float dR = __builtin_amdgcn_sqrtf(r2);

            // m^2(i,j) = m2_i + m2_j + 2*(E_i E_j - p_i . p_j)
            float c = a.z * E;
            c = fmaf(-bb.x, px, c);
            c = fmaf(-bb.y, py, c);
            c = fmaf(-bb.z, pz, c);
            const float m2 = fmaf(2.0f, c, a.w + m2n);
            const float mass = __builtin_amdgcn_sqrtf(fmaxf(m2, 1e-12f));

            outp[(size_t)r * NN] = make_float2(dR, mass);
        }

        // Phase 1 for next strip into the other LDS buffer (no race: the
        // buffer being written was last read in strip t-1, already synced).
        if (t < SPT - 1) {
            node_features(nv, eta, phi, E, px, py, pz, m2n);
            f4 a; a.x = eta; a.y = phi; a.z = E;  a.w = m2n;
            f4 bb; bb.x = px; bb.y = py; bb.z = pz; bb.w = 0.0f;
            s_a[buf ^ 1][tid] = a;
            s_b[buf ^ 1][tid] = bb;
            __syncthreads();
        }
    }
}

extern "C" void kernel_launch(void* const* d_in, const int* in_sizes, int n_in,
                              void* d_out, int out_size, void* d_ws, size_t ws_size,
                              hipStream_t stream) {
    const float* x = (const float*)d_in[0];
    float* out = (float*)d_out;
    edge_kernel<<<dim3(GRID), dim3(256), 0, stream>>>(x, out);
}